// Round 2
// baseline (229.928 us; speedup 1.0000x reference)
//
#include <hip/hip_runtime.h>
#include <stdint.h>

// DilatedMask: mask = (x == 0), then 33x33 sliding max (SAME) == binary dilation.
// Strategy: bitpack mask (1 bit/px, 4 MiB total -> lives in L2), OR-based
// separable dilation on packed words, unpack to INT32 0/1 (reference output
// dtype is uint8 -> harness reads d_out as int32). HBM traffic ~= 268 MB
// (compulsory 128 read + 128 write + ~8 packed), roofline ~43 us.

#define NIMG 8
#define HH_ 2048
#define WW_PX 2048
#define WW 32          // uint64 words per row (2048 bits)
#define RAD 16

// spread bit k -> bit 4k (16 bits -> 64 bits)
__device__ __forceinline__ uint64_t spread4(uint64_t x) {
  x &= 0xFFFFULL;
  x = (x | (x << 24)) & 0x000000FF000000FFULL;
  x = (x | (x << 12)) & 0x000F000F000F000FULL;
  x = (x | (x << 6))  & 0x0303030303030303ULL;
  x = (x | (x << 3))  & 0x1111111111111111ULL;
  return x;
}

// K1: pack. Each lane loads float4 (4 px); one wave covers 256 px = 4 words.
// Pixel p = 4*lane + q  ->  word j = p>>6, bit p&63. Reassemble from 4 ballots.
__global__ __launch_bounds__(256) void pack_kernel(const float* __restrict__ x,
                                                   uint64_t* __restrict__ packed) {
  const long long px0 = ((long long)blockIdx.x * 256 + threadIdx.x) * 4;
  const float4 v = *(const float4*)(x + px0);
  const unsigned long long m0 = __ballot(v.x == 0.0f);
  const unsigned long long m1 = __ballot(v.y == 0.0f);
  const unsigned long long m2 = __ballot(v.z == 0.0f);
  const unsigned long long m3 = __ballot(v.w == 0.0f);
  const int lane = threadIdx.x & 63;
  if ((lane & 15) == 0) {
    const int sh = lane;  // j*16 where j = lane>>4
    uint64_t w = spread4(m0 >> sh)
               | (spread4(m1 >> sh) << 1)
               | (spread4(m2 >> sh) << 2)
               | (spread4(m3 >> sh) << 3);
    packed[px0 >> 6] = w;   // px0>>6 == wave_word_base + j for these lanes
  }
}

// K2: block = 8 rows x 32 words (256 threads). Vertical OR (33 taps, clamped),
// horizontal OR of +-16 bit shifts with neighbor-word carries, unpack+store.
__global__ __launch_bounds__(256) void dilate_kernel(const uint64_t* __restrict__ packed,
                                                     int* __restrict__ out) {
  __shared__ uint64_t vall[8][WW + 2];  // +2 zero guard columns
  __shared__ uint64_t hrow[8][WW];

  const int t = threadIdx.x;
  const int w = t & 31;
  const int r = t >> 5;                       // row within block, 0..7
  const int gr0 = blockIdx.x * 8;             // global row base (never straddles images)
  const int n = gr0 >> 11;
  const int h = (gr0 & 2047) + r;
  const uint64_t* base = packed + (long long)n * (HH_ * WW);

  uint64_t v = 0;
#pragma unroll
  for (int dh = -RAD; dh <= RAD; ++dh) {
    int hh = h + dh;
    hh = hh < 0 ? 0 : (hh > HH_ - 1 ? HH_ - 1 : hh);  // clamp == clipped window (OR-idempotent)
    v |= base[hh * WW + w];
  }
  vall[r][w + 1] = v;
  if (w == 0) { vall[r][0] = 0; vall[r][WW + 1] = 0; }
  __syncthreads();

  {
    const uint64_t p = vall[r][w];
    const uint64_t c = vall[r][w + 1];
    const uint64_t nx = vall[r][w + 2];
    uint64_t res = c;
#pragma unroll
    for (int s = 1; s <= RAD; ++s) {
      res |= (c >> s) | (nx << (64 - s));
      res |= (c << s) | (p >> (64 - s));
    }
    hrow[r][w] = res;
  }
  __syncthreads();

  // 8 rows x 2048 px = 4096 int4 stores, 16 per thread, coalesced.
  int* obase = out + (long long)gr0 * WW_PX;
#pragma unroll
  for (int it = 0; it < 16; ++it) {
    const int f = it * 256 + t;          // int4 index in tile
    const int row_l = f >> 9;            // 512 int4 per row
    const int wi = (f >> 4) & 31;        // 16 int4 per word
    const int sh = (f & 15) * 4;
    const uint64_t bits = hrow[row_l][wi] >> sh;
    int4 o;
    o.x = (int)(bits & 1);
    o.y = (int)((bits >> 1) & 1);
    o.z = (int)((bits >> 2) & 1);
    o.w = (int)((bits >> 3) & 1);
    *(int4*)(obase + (long long)f * 4) = o;
  }
}

extern "C" void kernel_launch(void* const* d_in, const int* in_sizes, int n_in,
                              void* d_out, int out_size, void* d_ws, size_t ws_size,
                              hipStream_t stream) {
  const float* x = (const float*)d_in[0];
  int* out = (int*)d_out;
  uint64_t* packed = (uint64_t*)d_ws;   // 8*2048*32*8 B = 4 MiB

  // K1: 33,554,432 px / (4 px/thread * 256 thread/block) = 32768 blocks
  hipLaunchKernelGGL(pack_kernel, dim3(32768), dim3(256), 0, stream, x, packed);
  // K2: 16384 global rows / 8 rows per block = 2048 blocks
  hipLaunchKernelGGL(dilate_kernel, dim3(2048), dim3(256), 0, stream, packed, out);
}

// Round 4
// 225.376 us; speedup vs baseline: 1.0202x; 1.0202x over previous
//
#include <hip/hip_runtime.h>
#include <stdint.h>

// DilatedMask: mask = (x == 0), then 33x33 sliding max (SAME) == binary dilation.
// Strategy: bitpack mask (1 bit/px, 4 MiB total -> L2-resident), OR-based
// separable dilation on packed words, unpack to INT32 0/1 (reference output
// dtype uint8 -> harness reads d_out via the int32 path). Compulsory HBM
// traffic = 128 MiB read + 128 MiB write ~= 42 us at 6.3 TB/s.

#define HH_ 2048
#define WW_PX 2048
#define WW 32          // uint64 words per row (2048 bits)
#define RAD 16
#define ROWS 16        // output rows per dilate block
#define TPB2 512

// native clang vector types: __builtin_nontemporal_* requires these
// (HIP_vector_type float4/int4 are structs and are rejected).
typedef float  vfloat4 __attribute__((ext_vector_type(4)));
typedef int    vint4   __attribute__((ext_vector_type(4)));

// spread bit k -> bit 4k (16 bits -> 64 bits)
__device__ __forceinline__ uint64_t spread4(uint64_t x) {
  x &= 0xFFFFULL;
  x = (x | (x << 24)) & 0x000000FF000000FFULL;
  x = (x | (x << 12)) & 0x000F000F000F000FULL;
  x = (x | (x << 6))  & 0x0303030303030303ULL;
  x = (x | (x << 3))  & 0x1111111111111111ULL;
  return x;
}

// K1: pack. Each lane loads float4 (4 px, non-temporal: streamed once);
// 4 ballots -> bit-spread reassembly -> 4 uint64 words per wave.
__global__ __launch_bounds__(256) void pack_kernel(const float* __restrict__ x,
                                                   uint64_t* __restrict__ packed) {
  const long long px0 = ((long long)blockIdx.x * 256 + threadIdx.x) * 4;
  const vfloat4 v = __builtin_nontemporal_load((const vfloat4*)(x + px0));
  const unsigned long long m0 = __ballot(v.x == 0.0f);
  const unsigned long long m1 = __ballot(v.y == 0.0f);
  const unsigned long long m2 = __ballot(v.z == 0.0f);
  const unsigned long long m3 = __ballot(v.w == 0.0f);
  const int lane = threadIdx.x & 63;
  if ((lane & 15) == 0) {
    const int sh = lane;  // j*16 where j = lane>>4
    uint64_t w = spread4(m0 >> sh)
               | (spread4(m1 >> sh) << 1)
               | (spread4(m2 >> sh) << 2)
               | (spread4(m3 >> sh) << 3);
    packed[px0 >> 6] = w;   // normal store: keep packed raster in L2 for K2
  }
}

// K2: block = 16 output rows x 32 words (512 threads).
// Stage 48 rows (16+2*RAD halo) in LDS once, vertical OR from LDS,
// horizontal OR of +-16 bit shifts with neighbor-word carries, unpack+store.
__global__ __launch_bounds__(TPB2) void dilate_kernel(const uint64_t* __restrict__ packed,
                                                      int* __restrict__ out) {
  __shared__ uint64_t stage[ROWS + 2 * RAD][WW];  // 48*32*8 = 12 KiB
  __shared__ uint64_t vall[ROWS][WW + 2];         // zero guard columns
  __shared__ uint64_t hrow[ROWS][WW];

  const int t = threadIdx.x;
  const int gr0 = blockIdx.x * ROWS;          // 2048 % 16 == 0: never straddles images
  const int n = gr0 >> 11;
  const int h0 = gr0 & 2047;
  const uint64_t* base = packed + (long long)n * (HH_ * WW);

  // cooperative stage: 48 rows x 32 words, coalesced (row-major), clamped
#pragma unroll
  for (int i = 0; i < (ROWS + 2 * RAD) * WW / TPB2; ++i) {
    const int idx = i * TPB2 + t;
    const int rr = idx >> 5;
    const int w_ = idx & 31;
    int hh = h0 + rr - RAD;
    hh = hh < 0 ? 0 : (hh > HH_ - 1 ? HH_ - 1 : hh);  // clamp == clipped SAME window (OR-idempotent)
    stage[rr][w_] = base[hh * WW + w_];
  }
  __syncthreads();

  const int w = t & 31;
  const int r = t >> 5;                       // 0..15
  uint64_t v = 0;
#pragma unroll
  for (int i = 0; i <= 2 * RAD; ++i) v |= stage[r + i][w];
  vall[r][w + 1] = v;
  if (w == 0) { vall[r][0] = 0; vall[r][WW + 1] = 0; }
  __syncthreads();

  {
    const uint64_t p = vall[r][w];
    const uint64_t c = vall[r][w + 1];
    const uint64_t nx = vall[r][w + 2];
    uint64_t res = c;
#pragma unroll
    for (int s = 1; s <= RAD; ++s) {
      res |= (c >> s) | (nx << (64 - s));
      res |= (c << s) | (p >> (64 - s));
    }
    hrow[r][w] = res;
  }
  __syncthreads();

  // 16 rows x 2048 px = 8192 int4 stores, 16 per thread, coalesced, non-temporal
  int* obase = out + (long long)gr0 * WW_PX;
#pragma unroll
  for (int it = 0; it < 16; ++it) {
    const int f = it * TPB2 + t;         // int4 index in tile
    const int row_l = f >> 9;            // 512 int4 per row
    const int wi = (f >> 4) & 31;        // 16 int4 per word
    const int sh = (f & 15) * 4;
    const uint64_t bits = hrow[row_l][wi] >> sh;
    vint4 o;
    o.x = (int)(bits & 1);
    o.y = (int)((bits >> 1) & 1);
    o.z = (int)((bits >> 2) & 1);
    o.w = (int)((bits >> 3) & 1);
    __builtin_nontemporal_store(o, (vint4*)(obase + (long long)f * 4));
  }
}

extern "C" void kernel_launch(void* const* d_in, const int* in_sizes, int n_in,
                              void* d_out, int out_size, void* d_ws, size_t ws_size,
                              hipStream_t stream) {
  const float* x = (const float*)d_in[0];
  int* out = (int*)d_out;
  uint64_t* packed = (uint64_t*)d_ws;   // 8*2048*32*8 B = 4 MiB, fully rewritten every call

  // K1: 33,554,432 px / (4 px/thread * 256 thread/block) = 32768 blocks
  hipLaunchKernelGGL(pack_kernel, dim3(32768), dim3(256), 0, stream, x, packed);
  // K2: 16384 global rows / 16 rows per block = 1024 blocks
  hipLaunchKernelGGL(dilate_kernel, dim3(1024), dim3(TPB2), 0, stream, packed, out);
}